// Round 1
// baseline (1243.795 us; speedup 1.0000x reference)
//
#include <hip/hip_runtime.h>
#include <hip/hip_bf16.h>
#include <stdint.h>

#define B_   8
#define L_   2048
#define D_   1024
#define NH_  32
#define M_   16
#define NM_  128
#define HD_  32
#define DI_  2048
#define BL_  16384
#define EPS_ 1e-6f

typedef __attribute__((ext_vector_type(8))) short  s16x8;
typedef __attribute__((ext_vector_type(4))) short  s16x4;
typedef __attribute__((ext_vector_type(8))) __bf16 bf16x8;
typedef __attribute__((ext_vector_type(4))) float  f32x4;

__device__ __forceinline__ float bf2f(short s){
  unsigned u = ((unsigned)(unsigned short)s) << 16;
  return __builtin_bit_cast(float, u);
}
__device__ __forceinline__ short f2bf(float f){
  unsigned u = __builtin_bit_cast(unsigned, f);
  u = u + 0x7FFFu + ((u >> 16) & 1u);   // RNE
  return (short)(u >> 16);
}
__device__ __forceinline__ float hsum32(float v){
  v += __shfl_xor(v, 1);  v += __shfl_xor(v, 2);  v += __shfl_xor(v, 4);
  v += __shfl_xor(v, 8);  v += __shfl_xor(v, 16);
  return v;
}

// ---------------- transpose + fp32->bf16 cast: out(Cc,R) = in(R,Cc)^T ------
__global__ __launch_bounds__(256) void transpose_cast(
    const float* __restrict__ in, short* __restrict__ out, int R, int Cc)
{
  __shared__ float t[32][33];
  const int lx = threadIdx.x & 31, ly = threadIdx.x >> 5;
  const int r0 = blockIdx.y * 32, c0 = blockIdx.x * 32;
  #pragma unroll
  for (int s = 0; s < 4; ++s){
    const int r = ly + s*8;
    t[r][lx] = in[(size_t)(r0 + r)*Cc + c0 + lx];
  }
  __syncthreads();
  #pragma unroll
  for (int s = 0; s < 4; ++s){
    const int r = ly + s*8;
    out[(size_t)(c0 + r)*R + r0 + lx] = f2bf(t[lx][r]);
  }
}

// ---------------- misc prep: lr_w cast + rope tables -----------------------
__global__ __launch_bounds__(256) void misc_prep(
    const float* __restrict__ lr_w, short* __restrict__ lrwb,
    float* __restrict__ ct, float* __restrict__ st)
{
  const int idx = blockIdx.x*256 + threadIdx.x;
  if (idx < NH_*D_){
    lrwb[idx] = f2bf(lr_w[idx]);
  } else {
    const int k = idx - NH_*D_;       // 0 .. L_*16-1
    const int l = k >> 4, j = k & 15;
    const float inv = powf(10000.f, -(float)j * (1.f/16.f));
    const float fr  = (float)l * inv;
    ct[k] = cosf(fr);
    st[k] = sinf(fr);
  }
}

// ---------------- row layernorm fp32 -> bf16 (D=1024) ----------------------
__global__ __launch_bounds__(256) void ln_rows(
    const float* __restrict__ in, const float* __restrict__ g,
    const float* __restrict__ bta, short* __restrict__ out)
{
  const int row = blockIdx.x, tid = threadIdx.x;
  const float4 v = ((const float4*)(in + (size_t)row*D_))[tid];
  float s  = v.x + v.y + v.z + v.w;
  float s2 = v.x*v.x + v.y*v.y + v.z*v.z + v.w*v.w;
  #pragma unroll
  for (int m = 1; m < 64; m <<= 1){ s += __shfl_xor(s, m); s2 += __shfl_xor(s2, m); }
  __shared__ float rs[4], rq[4];
  if ((tid & 63) == 0){ rs[tid>>6] = s; rq[tid>>6] = s2; }
  __syncthreads();
  s  = rs[0] + rs[1] + rs[2] + rs[3];
  s2 = rq[0] + rq[1] + rq[2] + rq[3];
  const float mu   = s  * (1.f/D_);
  const float var  = s2 * (1.f/D_) - mu*mu;
  const float rstd = rsqrtf(var + EPS_);
  const float4 gg = ((const float4*)g)[tid];
  const float4 bb = ((const float4*)bta)[tid];
  s16x4 o;
  o[0] = f2bf((v.x - mu)*rstd*gg.x + bb.x);
  o[1] = f2bf((v.y - mu)*rstd*gg.y + bb.y);
  o[2] = f2bf((v.z - mu)*rstd*gg.z + bb.z);
  o[3] = f2bf((v.w - mu)*rstd*gg.w + bb.w);
  ((s16x4*)(out + (size_t)row*D_))[tid] = o;
}

// ---------------- bf16 MFMA GEMM: C(Mr,N) = A(Mr,K) @ Bt(N,K)^T ------------
// 128x128 tile, BK=32, 4 waves of 64x64. Epilogue: +bias, +res, relu, out f32/bf16
template<int ACT, int OUTBF, int BIAS, int RES>
__global__ __launch_bounds__(256) void gemm_bt(
    const short* __restrict__ A, const short* __restrict__ Bt,
    const float* __restrict__ bias, const float* __restrict__ res,
    float* __restrict__ Cf, short* __restrict__ Cb,
    int Mr, int N, int K)
{
  __shared__ __align__(16) short As[128*32];
  __shared__ __align__(16) short Bs[128*32];
  const int tid  = threadIdx.x;
  const int lane = tid & 63, wid = tid >> 6;
  const int row0 = blockIdx.y * 128, col0 = blockIdx.x * 128;
  const int wm = (wid >> 1) * 64, wn = (wid & 1) * 64;
  f32x4 acc[4][4] = {};

  const int sr = tid >> 2, sk = (tid & 3) * 8;
  const short* gA0 = A  + (size_t)(row0 + sr)      * K + sk;
  const short* gA1 = A  + (size_t)(row0 + sr + 64) * K + sk;
  const short* gB0 = Bt + (size_t)(col0 + sr)      * K + sk;
  const short* gB1 = Bt + (size_t)(col0 + sr + 64) * K + sk;
  short* lA0 = As + 8*tid;  short* lA1 = As + 2048 + 8*tid;
  short* lB0 = Bs + 8*tid;  short* lB1 = Bs + 2048 + 8*tid;

  const int fr = lane & 15, fk = (lane >> 4) * 8;
  const int nK = K >> 5;
  for (int kt = 0; kt < nK; ++kt){
    __syncthreads();
    const int ko = kt << 5;
    *(s16x8*)lA0 = *(const s16x8*)(gA0 + ko);
    *(s16x8*)lA1 = *(const s16x8*)(gA1 + ko);
    *(s16x8*)lB0 = *(const s16x8*)(gB0 + ko);
    *(s16x8*)lB1 = *(const s16x8*)(gB1 + ko);
    __syncthreads();
    bf16x8 af[4], bfv[4];
    #pragma unroll
    for (int f = 0; f < 4; ++f){
      af[f]  = __builtin_bit_cast(bf16x8, *(const s16x8*)(As + (wm + f*16 + fr)*32 + fk));
      bfv[f] = __builtin_bit_cast(bf16x8, *(const s16x8*)(Bs + (wn + f*16 + fr)*32 + fk));
    }
    #pragma unroll
    for (int i = 0; i < 4; ++i)
      #pragma unroll
      for (int j = 0; j < 4; ++j)
        acc[i][j] = __builtin_amdgcn_mfma_f32_16x16x32_bf16(af[i], bfv[j], acc[i][j], 0, 0, 0);
  }
  const int cr = (lane >> 4) * 4, cc = lane & 15;
  #pragma unroll
  for (int i = 0; i < 4; ++i){
    #pragma unroll
    for (int j = 0; j < 4; ++j){
      const int gc = col0 + wn + j*16 + cc;
      float bv = 0.f;
      if (BIAS) bv = bias[gc];
      #pragma unroll
      for (int r = 0; r < 4; ++r){
        const int gr = row0 + wm + i*16 + cr + r;
        float v = acc[i][j][r] + bv;
        if (RES) v += res[(size_t)gr*N + gc];
        if (ACT == 1) v = fmaxf(v, 0.f);
        if (OUTBF) Cb[(size_t)gr*N + gc] = f2bf(v);
        else       Cf[(size_t)gr*N + gc] = v;
      }
    }
  }
}

// ---------------- eta: sigmoid(x . lr_w[h] + lr_b[h]) / HD -----------------
__global__ __launch_bounds__(256) void eta_kernel(
    const short* __restrict__ xb, const short* __restrict__ lrwb,
    const float* __restrict__ lr_b, float* __restrict__ eta)
{
  __shared__ __align__(16) short wl[NH_*D_];   // 64 KB
  __shared__ __align__(16) short xr[D_];
  const int tid = threadIdx.x;
  const int wid = tid >> 6, lane = tid & 63;
  #pragma unroll
  for (int s = 0; s < 16; ++s){
    const int e8 = tid + 256*s;
    ((s16x8*)wl)[e8] = ((const s16x8*)lrwb)[e8];
  }
  for (int tk = 0; tk < 32; ++tk){
    const int token = blockIdx.x*32 + tk;
    __syncthreads();
    if (tid < 128) ((s16x8*)xr)[tid] = ((const s16x8*)(xb + (size_t)token*D_))[tid];
    __syncthreads();
    const s16x8 x0 = ((const s16x8*)xr)[lane*2];
    const s16x8 x1 = ((const s16x8*)xr)[lane*2 + 1];
    #pragma unroll 1
    for (int hh = 0; hh < 8; ++hh){
      const int h = wid*8 + hh;
      const s16x8 w0 = ((const s16x8*)(wl + h*D_))[lane*2];
      const s16x8 w1 = ((const s16x8*)(wl + h*D_))[lane*2 + 1];
      float s = 0.f;
      #pragma unroll
      for (int e = 0; e < 8; ++e)
        s += bf2f(x0[e])*bf2f(w0[e]) + bf2f(x1[e])*bf2f(w1[e]);
      #pragma unroll
      for (int m = 1; m < 64; m <<= 1) s += __shfl_xor(s, m);
      if (lane == 0){
        const float v = 1.f/(1.f + __expf(-(s + lr_b[h]))) * (1.f/32.f);
        const int bidx = token >> 11, l = token & (L_-1), n = l >> 4, im = l & 15;
        eta[(((size_t)bidx*NH_ + h)*NM_ + n)*M_ + im] = v;
      }
    }
  }
}

// ---------------- RoPE in place on Q,K halves of QKV -----------------------
__global__ __launch_bounds__(256) void rope_apply(
    short* __restrict__ QKV, const float* __restrict__ ct, const float* __restrict__ st)
{
  const size_t idx = (size_t)blockIdx.x*256 + threadIdx.x;  // B*L*NH*16
  const int part  = blockIdx.y;                              // 0=Q, 1=K
  const int token = (int)(idx >> 9);
  const int r     = (int)(idx & 511);
  const int hh = r >> 4, j = r & 15;
  const int l  = token & (L_-1);
  const size_t base = (size_t)token*3072 + part*1024 + hh*32 + j;
  const float x0 = bf2f(QKV[base]), x1 = bf2f(QKV[base + 16]);
  const float c = ct[l*16 + j], s = st[l*16 + j];
  QKV[base]      = f2bf(x0*c - x1*s);
  QKV[base + 16] = f2bf(x1*c + x0*s);
}

// ---------------- TTT scan: one block per (b,h), 512 threads ---------------
__global__ __launch_bounds__(512) void scan_kernel(
    const short* __restrict__ QKV, const float* __restrict__ eta,
    const float* __restrict__ W1, const float* __restrict__ b1,
    const float* __restrict__ tdelta,
    const float* __restrict__ lng, const float* __restrict__ lnb,
    float* __restrict__ out)
{
  const int h = blockIdx.x, b = blockIdx.y;
  const int tid = threadIdx.x;
  const int i = tid >> 5, d = tid & 31;   // i: 0..15 row, d: 0..31 dim
  __shared__ float W[32][32];
  __shared__ float bb[32];
  __shared__ float qs[16][33], ks[16][33], vs[16][33], gs[16][33];
  __shared__ float at[16][17];
  __shared__ float lrs[16], toks[16];

  W[i][d]      = W1[(size_t)h*1024 + i*32 + d];
  W[i + 16][d] = W1[(size_t)h*1024 + (i + 16)*32 + d];
  if (tid < 32) bb[tid] = b1[h*32 + tid];
  if (tid < 16) toks[tid] = fmaxf(1.f/(float)(tid + 1) + tdelta[tid], 0.f);
  const float lwd = lng[h*32 + d], lbd = lnb[h*32 + d];
  const size_t qrow0 = (size_t)b*L_*3072 + (size_t)h*32 + d;
  const size_t erow0 = ((size_t)b*NH_ + h)*NM_*M_;

  for (int n = 0; n < NM_; ++n){
    __syncthreads();   // protects W/bb writes + q/k/v/gs reuse from prev iter
    {
      const size_t rb = qrow0 + (size_t)(n*16 + i)*3072;
      qs[i][d] = bf2f(QKV[rb]);
      ks[i][d] = bf2f(QKV[rb + 1024]);
      vs[i][d] = bf2f(QKV[rb + 2048]);
    }
    if (tid < 16) lrs[tid] = eta[erow0 + (size_t)n*M_ + tid];
    __syncthreads();

    // ---- Z1 = k @ W + b ; grad = ln_l2_bwd(Z1, v-k)
    float z0=0, z1=0, z2=0, z3=0;
    #pragma unroll
    for (int c = 0; c < 32; c += 4){
      z0 += ks[i][c  ]*W[c  ][d];
      z1 += ks[i][c+1]*W[c+1][d];
      z2 += ks[i][c+2]*W[c+2][d];
      z3 += ks[i][c+3]*W[c+3][d];
    }
    const float z    = bb[d] + ((z0+z1)+(z2+z3));
    const float mu   = hsum32(z) * (1.f/32.f);
    const float zc   = z - mu;
    const float var  = hsum32(zc*zc) * (1.f/32.f);
    const float stdv = sqrtf(var + EPS_);
    const float xh   = zc / stdv;
    const float tgt  = vs[i][d] - ks[i][d];
    const float gxh  = (xh*lwd + lbd - tgt)*lwd;
    const float sg   = hsum32(gxh);
    const float sgx  = hsum32(gxh*xh);
    gs[i][d] = (32.f*gxh - sg - xh*sgx) / (32.f*stdv);

    // ---- Attn1 raw = q @ k^T (tril applied implicitly later)
    if (tid < 256){
      const int i2 = tid >> 4, j = tid & 15;
      float a0=0, a1=0, a2=0, a3=0;
      #pragma unroll
      for (int c = 0; c < 32; c += 4){
        a0 += qs[i2][c  ]*ks[j][c  ];
        a1 += qs[i2][c+1]*ks[j][c+1];
        a2 += qs[i2][c+2]*ks[j][c+2];
        a3 += qs[i2][c+3]*ks[j][c+3];
      }
      at[i2][j] = (a0+a1)+(a2+a3);
    }
    __syncthreads();

    // ---- Z1_bar = q@W + b - tok[i] * sum_{j<=i} lr[j]*(1+Attn[i][j])*grad[j]
    float y0=0, y1=0, y2=0, y3=0;
    #pragma unroll
    for (int c = 0; c < 32; c += 4){
      y0 += qs[i][c  ]*W[c  ][d];
      y1 += qs[i][c+1]*W[c+1][d];
      y2 += qs[i][c+2]*W[c+2][d];
      y3 += qs[i][c+3]*W[c+3][d];
    }
    float zb = bb[d] + ((y0+y1)+(y2+y3));
    float acc2 = 0.f;
    for (int j = 0; j <= i; ++j)
      acc2 += lrs[j]*(1.f + at[i][j])*gs[j][d];
    zb -= toks[i]*acc2;

    // ---- out = q + ln_fwd(Z1_bar)
    const float mu2  = hsum32(zb) * (1.f/32.f);
    const float zc2  = zb - mu2;
    const float var2 = hsum32(zc2*zc2) * (1.f/32.f);
    out[((size_t)b*L_ + n*16 + i)*D_ + h*32 + d] =
        qs[i][d] + zc2*rsqrtf(var2 + EPS_)*lwd + lbd;
    __syncthreads();   // all W/gs reads done before update

    // ---- W -= (last_e*k)^T @ grad ; b -= sum(last_e*grad)
    const float lef = toks[15];
    float u0=0, u1=0, ub=0;
    #pragma unroll
    for (int j = 0; j < 16; ++j){
      const float leg = lef*lrs[j]*gs[j][d];
      u0 += leg*ks[j][i];
      u1 += leg*ks[j][i + 16];
      ub += leg;
    }
    W[i][d]      -= u0;
    W[i + 16][d] -= u1;
    if (i == 0) bb[d] -= ub;
  }
}

// ---------------------------------------------------------------------------
extern "C" void kernel_launch(void* const* d_in, const int* in_sizes, int n_in,
                              void* d_out, int out_size, void* d_ws, size_t ws_size,
                              hipStream_t stream)
{
  const float* enc    = (const float*)d_in[0];
  const float* ln0_g  = (const float*)d_in[1];
  const float* ln0_b  = (const float*)d_in[2];
  const float* Wq     = (const float*)d_in[3];
  const float* Wk     = (const float*)d_in[4];
  const float* Wv     = (const float*)d_in[5];
  const float* Wo     = (const float*)d_in[6];
  const float* W1     = (const float*)d_in[7];
  const float* b1     = (const float*)d_in[8];
  const float* tdelta = (const float*)d_in[9];
  const float* lr_w   = (const float*)d_in[10];
  const float* lr_b   = (const float*)d_in[11];
  const float* ttt_g  = (const float*)d_in[12];
  const float* ttt_b  = (const float*)d_in[13];
  const float* post_g = (const float*)d_in[14];
  const float* post_b = (const float*)d_in[15];
  const float* ffn_g  = (const float*)d_in[16];
  const float* ffn_b  = (const float*)d_in[17];
  const float* fw1    = (const float*)d_in[18];
  const float* fb1    = (const float*)d_in[19];
  const float* fw2    = (const float*)d_in[20];
  const float* fb2    = (const float*)d_in[21];

  char* ws = (char*)d_ws;
  // region layout (bytes); XB/SCAN overlap (XB dead before scan);
  // YB/HB/T1 live in the dead QKV region after the scan.
  short* QKV   = (short*)(ws + 0);            // 100,663,296 B
  short* XB    = (short*)(ws + 100663296);    //  33,554,432 B
  float* SCAN  = (float*)(ws + 100663296);    //  67,108,864 B (over XB)
  short* WQKVT = (short*)(ws + 167772160);    //   6,291,456 B
  short* WOT   = (short*)(ws + 174063616);    //   2,097,152 B
  short* FW1T  = (short*)(ws + 176160768);    //   4,194,304 B
  short* FW2T  = (short*)(ws + 180355072);    //   4,194,304 B
  short* LRWB  = (short*)(ws + 184549376);    //      65,536 B
  float* CT    = (float*)(ws + 184614912);    //     131,072 B
  float* ST    = (float*)(ws + 184745984);    //     131,072 B
  float* ETA   = (float*)(ws + 184877056);    //   2,097,152 B
  short* YB    = (short*)(ws + 0);            // reuse (post-scan)
  short* HB    = (short*)(ws + 0);            // reuse (post-Wo)
  short* T1    = (short*)(ws + 35651584);     // reuse (post-scan)
  float* R2    = (float*)d_out;

  dim3 b256(256);
  // weight transposes (fp32 -> bf16, (K,N) -> (N,K))
  transpose_cast<<<dim3(32,32), b256, 0, stream>>>(Wq,  WQKVT,           D_, D_);
  transpose_cast<<<dim3(32,32), b256, 0, stream>>>(Wk,  WQKVT + 1048576, D_, D_);
  transpose_cast<<<dim3(32,32), b256, 0, stream>>>(Wv,  WQKVT + 2097152, D_, D_);
  transpose_cast<<<dim3(32,32), b256, 0, stream>>>(Wo,  WOT,             D_, D_);
  transpose_cast<<<dim3(64,32), b256, 0, stream>>>(fw1, FW1T,            D_, DI_);
  transpose_cast<<<dim3(32,64), b256, 0, stream>>>(fw2, FW2T,            DI_, D_);
  misc_prep<<<dim3(256), b256, 0, stream>>>(lr_w, LRWB, CT, ST);

  // LN0 -> xb (bf16)
  ln_rows<<<BL_, b256, 0, stream>>>(enc, ln0_g, ln0_b, XB);
  // fused QKV projection (bf16 out)
  gemm_bt<0,1,0,0><<<dim3(24,128), b256, 0, stream>>>(XB, WQKVT, nullptr, nullptr,
                                                      nullptr, QKV, BL_, 3072, D_);
  // ttt learning rates
  eta_kernel<<<dim3(512), b256, 0, stream>>>(XB, LRWB, lr_b, ETA);
  // RoPE in place on Q,K
  rope_apply<<<dim3(32768,2), b256, 0, stream>>>(QKV, CT, ST);
  // TTT scan
  scan_kernel<<<dim3(NH_, B_), dim3(512), 0, stream>>>(QKV, ETA, W1, b1, tdelta,
                                                       ttt_g, ttt_b, SCAN);
  // post-LN -> yb, Wo projection + residual -> d_out (= r2)
  ln_rows<<<BL_, b256, 0, stream>>>(SCAN, post_g, post_b, YB);
  gemm_bt<0,0,0,1><<<dim3(8,128), b256, 0, stream>>>(YB, WOT, nullptr, enc,
                                                     R2, nullptr, BL_, D_, D_);
  // FFN
  ln_rows<<<BL_, b256, 0, stream>>>(R2, ffn_g, ffn_b, HB);
  gemm_bt<1,1,1,0><<<dim3(16,128), b256, 0, stream>>>(HB, FW1T, fb1, nullptr,
                                                      nullptr, T1, BL_, DI_, D_);
  gemm_bt<0,0,1,1><<<dim3(8,128), b256, 0, stream>>>(T1, FW2T, fb2, R2,
                                                     R2, nullptr, BL_, D_, DI_);
}

// Round 2
// 1054.777 us; speedup vs baseline: 1.1792x; 1.1792x over previous
//
#include <hip/hip_runtime.h>
#include <hip/hip_bf16.h>
#include <stdint.h>

#define B_   8
#define L_   2048
#define D_   1024
#define NH_  32
#define M_   16
#define NM_  128
#define HD_  32
#define DI_  2048
#define BL_  16384
#define EPS_ 1e-6f

typedef __attribute__((ext_vector_type(8))) short  s16x8;
typedef __attribute__((ext_vector_type(4))) short  s16x4;
typedef __attribute__((ext_vector_type(8))) __bf16 bf16x8;
typedef __attribute__((ext_vector_type(4))) float  f32x4;

__device__ __forceinline__ float bf2f(short s){
  unsigned u = ((unsigned)(unsigned short)s) << 16;
  return __builtin_bit_cast(float, u);
}
__device__ __forceinline__ short f2bf(float f){
  unsigned u = __builtin_bit_cast(unsigned, f);
  u = u + 0x7FFFu + ((u >> 16) & 1u);   // RNE
  return (short)(u >> 16);
}
__device__ __forceinline__ float hsum32(float v){
  v += __shfl_xor(v, 1);  v += __shfl_xor(v, 2);  v += __shfl_xor(v, 4);
  v += __shfl_xor(v, 8);  v += __shfl_xor(v, 16);
  return v;
}
// async global->LDS, 16B per lane (dest = wave-uniform base + lane*16)
__device__ __forceinline__ void gl16(const void* g, void* l){
  __builtin_amdgcn_global_load_lds(
      (const __attribute__((address_space(1))) void*)g,
      (__attribute__((address_space(3))) void*)l, 16, 0, 0);
}

// ---------------- transpose + fp32->bf16 cast: out(Cc,R) = in(R,Cc)^T ------
__global__ __launch_bounds__(256) void transpose_cast(
    const float* __restrict__ in, short* __restrict__ out, int R, int Cc)
{
  __shared__ float t[32][33];
  const int lx = threadIdx.x & 31, ly = threadIdx.x >> 5;
  const int r0 = blockIdx.y * 32, c0 = blockIdx.x * 32;
  #pragma unroll
  for (int s = 0; s < 4; ++s){
    const int r = ly + s*8;
    t[r][lx] = in[(size_t)(r0 + r)*Cc + c0 + lx];
  }
  __syncthreads();
  #pragma unroll
  for (int s = 0; s < 4; ++s){
    const int r = ly + s*8;
    out[(size_t)(c0 + r)*R + r0 + lx] = f2bf(t[lx][r]);
  }
}

// ---------------- misc prep: lr_w cast + rope tables -----------------------
__global__ __launch_bounds__(256) void misc_prep(
    const float* __restrict__ lr_w, short* __restrict__ lrwb,
    float* __restrict__ ct, float* __restrict__ st)
{
  const int idx = blockIdx.x*256 + threadIdx.x;
  if (idx < NH_*D_){
    lrwb[idx] = f2bf(lr_w[idx]);
  } else {
    const int k = idx - NH_*D_;       // 0 .. L_*16-1
    const int l = k >> 4, j = k & 15;
    const float inv = powf(10000.f, -(float)j * (1.f/16.f));
    const float fr  = (float)l * inv;
    ct[k] = cosf(fr);
    st[k] = sinf(fr);
  }
}

// ---------------- row layernorm fp32 -> bf16 (D=1024) ----------------------
__global__ __launch_bounds__(256) void ln_rows(
    const float* __restrict__ in, const float* __restrict__ g,
    const float* __restrict__ bta, short* __restrict__ out)
{
  const int row = blockIdx.x, tid = threadIdx.x;
  const float4 v = ((const float4*)(in + (size_t)row*D_))[tid];
  float s  = v.x + v.y + v.z + v.w;
  float s2 = v.x*v.x + v.y*v.y + v.z*v.z + v.w*v.w;
  #pragma unroll
  for (int m = 1; m < 64; m <<= 1){ s += __shfl_xor(s, m); s2 += __shfl_xor(s2, m); }
  __shared__ float rs[4], rq[4];
  if ((tid & 63) == 0){ rs[tid>>6] = s; rq[tid>>6] = s2; }
  __syncthreads();
  s  = rs[0] + rs[1] + rs[2] + rs[3];
  s2 = rq[0] + rq[1] + rq[2] + rq[3];
  const float mu   = s  * (1.f/D_);
  const float var  = s2 * (1.f/D_) - mu*mu;
  const float rstd = rsqrtf(var + EPS_);
  const float4 gg = ((const float4*)g)[tid];
  const float4 bb = ((const float4*)bta)[tid];
  s16x4 o;
  o[0] = f2bf((v.x - mu)*rstd*gg.x + bb.x);
  o[1] = f2bf((v.y - mu)*rstd*gg.y + bb.y);
  o[2] = f2bf((v.z - mu)*rstd*gg.z + bb.z);
  o[3] = f2bf((v.w - mu)*rstd*gg.w + bb.w);
  ((s16x4*)(out + (size_t)row*D_))[tid] = o;
}

// ---------------- bf16 MFMA GEMM: C(Mr,N) = A(Mr,K) @ Bt(N,K)^T ------------
// 128x128 tile, BK=32, 4 waves of 64x64. global_load_lds staging.
// QKVOUT: fused RoPE + scan-layout output [(b,h)][n][part][i][d]
template<int ACT, int OUTBF, int BIAS, int RES, int QKVOUT>
__global__ __launch_bounds__(256) void gemm_bt(
    const short* __restrict__ A, const short* __restrict__ Bt,
    const float* __restrict__ bias, const float* __restrict__ res,
    float* __restrict__ Cf, short* __restrict__ Cb,
    const float* __restrict__ ct, const float* __restrict__ st,
    int Mr, int N, int K)
{
  __shared__ __align__(16) short As[128*32];
  __shared__ __align__(16) short Bs[128*32];
  const int tid  = threadIdx.x;
  const int lane = tid & 63, wid = tid >> 6;
  const int row0 = blockIdx.y * 128, col0 = blockIdx.x * 128;
  const int wm = (wid >> 1) * 64, wn = (wid & 1) * 64;
  f32x4 acc[4][4] = {};

  const int sr = tid >> 2, sk = (tid & 3) * 8;
  const short* gA0 = A  + (size_t)(row0 + sr)      * K + sk;
  const short* gA1 = A  + (size_t)(row0 + sr + 64) * K + sk;
  const short* gB0 = Bt + (size_t)(col0 + sr)      * K + sk;
  const short* gB1 = Bt + (size_t)(col0 + sr + 64) * K + sk;
  short* lA0 = As + 8*tid;  short* lA1 = As + 2048 + 8*tid;
  short* lB0 = Bs + 8*tid;  short* lB1 = Bs + 2048 + 8*tid;

  const int fr = lane & 15, fk = (lane >> 4) * 8;
  const int nK = K >> 5;
  for (int kt = 0; kt < nK; ++kt){
    __syncthreads();
    const int ko = kt << 5;
    gl16(gA0 + ko, lA0);
    gl16(gA1 + ko, lA1);
    gl16(gB0 + ko, lB0);
    gl16(gB1 + ko, lB1);
    asm volatile("s_waitcnt vmcnt(0)" ::: "memory");
    __syncthreads();
    bf16x8 af[4], bfv[4];
    #pragma unroll
    for (int f = 0; f < 4; ++f){
      af[f]  = __builtin_bit_cast(bf16x8, *(const s16x8*)(As + (wm + f*16 + fr)*32 + fk));
      bfv[f] = __builtin_bit_cast(bf16x8, *(const s16x8*)(Bs + (wn + f*16 + fr)*32 + fk));
    }
    #pragma unroll
    for (int i = 0; i < 4; ++i)
      #pragma unroll
      for (int j = 0; j < 4; ++j)
        acc[i][j] = __builtin_amdgcn_mfma_f32_16x16x32_bf16(af[i], bfv[j], acc[i][j], 0, 0, 0);
  }
  const int cr = (lane >> 4) * 4, cc = lane & 15;
  if (QKVOUT){
    const int part = col0 >> 10;        // uniform per block (1024 % 128 == 0)
    #pragma unroll
    for (int i = 0; i < 4; ++i){
      #pragma unroll
      for (int r = 0; r < 4; ++r){
        const int gr = row0 + wm + i*16 + cr + r;
        const int bidx = gr >> 11, l = gr & (L_-1);
        const int nn = l >> 4, ii = l & 15;
        if (part < 2){
          const float cv = ct[l*16 + cc], sv = st[l*16 + cc];
          #pragma unroll
          for (int jp = 0; jp < 2; ++jp){
            const int j0 = jp*2;
            const int gc = col0 + wn + j0*16 + cc;
            const int hh = (gc & 1023) >> 5;
            const float x0 = acc[i][j0][r], x1 = acc[i][j0+1][r];
            short* qb = Cb + ((size_t)(bidx*NH_ + hh)*NM_ + nn)*1536 + part*512 + ii*32 + cc;
            qb[0]  = f2bf(x0*cv - x1*sv);
            qb[16] = f2bf(x1*cv + x0*sv);
          }
        } else {
          #pragma unroll
          for (int j = 0; j < 4; ++j){
            const int gc = col0 + wn + j*16 + cc;
            const int hh = (gc & 1023) >> 5, dd = gc & 31;
            Cb[((size_t)(bidx*NH_ + hh)*NM_ + nn)*1536 + 1024 + ii*32 + dd] = f2bf(acc[i][j][r]);
          }
        }
      }
    }
    return;
  }
  #pragma unroll
  for (int i = 0; i < 4; ++i){
    #pragma unroll
    for (int j = 0; j < 4; ++j){
      const int gc = col0 + wn + j*16 + cc;
      float bv = 0.f;
      if (BIAS) bv = bias[gc];
      #pragma unroll
      for (int r = 0; r < 4; ++r){
        const int gr = row0 + wm + i*16 + cr + r;
        float v = acc[i][j][r] + bv;
        if (RES) v += res[(size_t)gr*N + gc];
        if (ACT == 1) v = fmaxf(v, 0.f);
        if (OUTBF) Cb[(size_t)gr*N + gc] = f2bf(v);
        else       Cf[(size_t)gr*N + gc] = v;
      }
    }
  }
}

// ---------------- eta: sigmoid(x . lr_w[h] + lr_b[h]) / HD -----------------
__global__ __launch_bounds__(256) void eta_kernel(
    const short* __restrict__ xb, const short* __restrict__ lrwb,
    const float* __restrict__ lr_b, float* __restrict__ eta)
{
  __shared__ __align__(16) short wl[NH_*D_];   // 64 KB
  __shared__ __align__(16) short xr[D_];
  const int tid = threadIdx.x;
  const int wid = tid >> 6, lane = tid & 63;
  #pragma unroll
  for (int s = 0; s < 16; ++s){
    const int e8 = tid + 256*s;
    ((s16x8*)wl)[e8] = ((const s16x8*)lrwb)[e8];
  }
  for (int tk = 0; tk < 32; ++tk){
    const int token = blockIdx.x*32 + tk;
    __syncthreads();
    if (tid < 128) ((s16x8*)xr)[tid] = ((const s16x8*)(xb + (size_t)token*D_))[tid];
    __syncthreads();
    const s16x8 x0 = ((const s16x8*)xr)[lane*2];
    const s16x8 x1 = ((const s16x8*)xr)[lane*2 + 1];
    #pragma unroll 1
    for (int hh = 0; hh < 8; ++hh){
      const int h = wid*8 + hh;
      const s16x8 w0 = ((const s16x8*)(wl + h*D_))[lane*2];
      const s16x8 w1 = ((const s16x8*)(wl + h*D_))[lane*2 + 1];
      float s = 0.f;
      #pragma unroll
      for (int e = 0; e < 8; ++e)
        s += bf2f(x0[e])*bf2f(w0[e]) + bf2f(x1[e])*bf2f(w1[e]);
      #pragma unroll
      for (int m = 1; m < 64; m <<= 1) s += __shfl_xor(s, m);
      if (lane == 0){
        const float v = 1.f/(1.f + __expf(-(s + lr_b[h]))) * (1.f/32.f);
        const int bidx = token >> 11, l = token & (L_-1), n = l >> 4, im = l & 15;
        eta[(((size_t)bidx*NH_ + h)*NM_ + n)*M_ + im] = v;
      }
    }
  }
}

// ---------------- TTT scan v2: double-buffered, prefetched, swizzled -------
// input QKVs: [(b*32+h)][n][part(q,k,v)][i(16)][d(32)] bf16
// LDS tiles stored f32, 16B-chunk XOR swizzle: chunk (part,rr,c4) at
// pos = part*128 + rr*8 + (c4 ^ (rr&7))
__device__ __forceinline__ int qidx(int part, int rr, int dd){
  const int pos = part*128 + rr*8 + ((dd >> 2) ^ (rr & 7));
  return pos*4 + (dd & 3);
}
__device__ __forceinline__ void stage_write(float* buf, int tid, const s16x8 v){
  #pragma unroll
  for (int q = 0; q < 2; ++q){
    const int ch = 2*tid + q;
    const int part = ch >> 7, rr = (ch >> 3) & 15, c4 = ch & 7;
    const int pos = part*128 + rr*8 + (c4 ^ (rr & 7));
    float4 f;
    f.x = bf2f(v[q*4+0]); f.y = bf2f(v[q*4+1]);
    f.z = bf2f(v[q*4+2]); f.w = bf2f(v[q*4+3]);
    ((float4*)buf)[pos] = f;
  }
}

__global__ __launch_bounds__(512) void scan_kernel(
    const short* __restrict__ QKVs, const float* __restrict__ eta,
    const float* __restrict__ W1, const float* __restrict__ b1,
    const float* __restrict__ tdelta, const float* __restrict__ lng,
    const float* __restrict__ lnb, float* __restrict__ out)
{
  const int h = blockIdx.x, b = blockIdx.y;
  const int tid = threadIdx.x;
  const int i = tid >> 5, d = tid & 31;
  __shared__ float W[32][32];
  __shared__ float bbv[32];
  __shared__ __align__(16) float qkv[2][1536];
  __shared__ float gsm[16][32];
  __shared__ float atm[16][16];
  __shared__ float lr2[2][16];
  __shared__ float toks[16];

  W[i][d]      = W1[h*1024 + i*32 + d];
  W[i + 16][d] = W1[h*1024 + (i+16)*32 + d];
  if (tid < 32) bbv[tid] = b1[h*32 + tid];
  if (tid < 16) toks[tid] = fmaxf(1.f/(float)(tid + 1) + tdelta[tid], 0.f);
  const float lwd = lng[h*32 + d], lbd = lnb[h*32 + d];

  const short* chain  = QKVs + (size_t)(b*NH_ + h)*NM_*1536;
  const float* echain = eta  + (size_t)(b*NH_ + h)*NM_*M_;
  const size_t outbase = (size_t)b*L_*D_ + h*32 + d;

  if (tid < 192) stage_write(qkv[0], tid, ((const s16x8*)chain)[tid]);
  if (tid >= 448 && tid < 464) lr2[0][tid - 448] = echain[tid - 448];
  __syncthreads();

  int cur = 0;
  for (int n = 0; n < NM_; ++n){
    // ---- prefetch issue for step n+1 (completes during compute)
    s16x8 pf; float pe = 0.f;
    const bool hp = (n + 1 < NM_);
    if (hp && tid < 192) pf = ((const s16x8*)(chain + (size_t)(n+1)*1536))[tid];
    if (hp && tid >= 448 && tid < 464) pe = echain[(size_t)(n+1)*16 + (tid - 448)];

    const float* bufc = qkv[cur];
    // ---- phase A: rows -> regs, z & y (share W reads), LN-bwd, attn
    float4 kr[8], qr[8];
    #pragma unroll
    for (int c4 = 0; c4 < 8; ++c4){
      kr[c4] = ((const float4*)bufc)[128 + i*8 + (c4 ^ (i & 7))];
      qr[c4] = ((const float4*)bufc)[      i*8 + (c4 ^ (i & 7))];
    }
    float z = bbv[d], y = z;
    #pragma unroll
    for (int c4 = 0; c4 < 8; ++c4){
      const float w0 = W[c4*4+0][d], w1 = W[c4*4+1][d];
      const float w2 = W[c4*4+2][d], w3 = W[c4*4+3][d];
      z += kr[c4].x*w0 + kr[c4].y*w1 + kr[c4].z*w2 + kr[c4].w*w3;
      y += qr[c4].x*w0 + qr[c4].y*w1 + qr[c4].z*w2 + qr[c4].w*w3;
    }
    const float mu   = hsum32(z) * (1.f/32.f);
    const float zc   = z - mu;
    const float var  = hsum32(zc*zc) * (1.f/32.f);
    const float stdv = sqrtf(var + EPS_);
    const float xh   = zc / stdv;
    const float tgt  = bufc[qidx(2, i, d)] - bufc[qidx(1, i, d)];
    const float gxh  = (xh*lwd + lbd - tgt)*lwd;
    const float sg   = hsum32(gxh);
    const float sgx  = hsum32(gxh*xh);
    gsm[i][d] = (32.f*gxh - sg - xh*sgx) / (32.f*stdv);

    if (tid < 256){
      const int i2 = tid >> 4, j = tid & 15;
      float a = 0.f;
      #pragma unroll
      for (int c4 = 0; c4 < 8; ++c4){
        const float4 qv = ((const float4*)bufc)[      i2*8 + (c4 ^ (i2 & 7))];
        const float4 kv = ((const float4*)bufc)[128 + j*8  + (c4 ^ (j  & 7))];
        a += qv.x*kv.x + qv.y*kv.y + qv.z*kv.z + qv.w*kv.w;
      }
      atm[i2][j] = a;
    }
    __syncthreads();

    // ---- phase B: z1_bar chain + W update (merged j-loop)
    float acc2 = 0.f, u0 = 0.f, u1 = 0.f, ub = 0.f;
    #pragma unroll
    for (int j = 0; j < 16; ++j){
      const float lr  = lr2[cur][j];
      const float g   = gsm[j][d];
      const float leg = lr*g;
      if (j <= i) acc2 += leg*(1.f + atm[i][j]);
      u0 += leg*bufc[qidx(1, j, i)];
      u1 += leg*bufc[qidx(1, j, i + 16)];
      ub += leg;
    }
    const float zb   = y - toks[i]*acc2;
    const float mu2  = hsum32(zb) * (1.f/32.f);
    const float zc2  = zb - mu2;
    const float var2 = hsum32(zc2*zc2) * (1.f/32.f);
    out[outbase + (size_t)(n*16 + i)*D_] =
        bufc[qidx(0, i, d)] + zc2*rsqrtf(var2 + EPS_)*lwd + lbd;

    const float lef = toks[15];
    W[i][d]      -= lef*u0;
    W[i + 16][d] -= lef*u1;
    if (i == 0) bbv[d] -= lef*ub;

    if (hp){
      if (tid < 192) stage_write(qkv[cur ^ 1], tid, pf);
      if (tid >= 448 && tid < 464) lr2[cur ^ 1][tid - 448] = pe;
    }
    cur ^= 1;
    __syncthreads();
  }
}

// ---------------------------------------------------------------------------
extern "C" void kernel_launch(void* const* d_in, const int* in_sizes, int n_in,
                              void* d_out, int out_size, void* d_ws, size_t ws_size,
                              hipStream_t stream)
{
  const float* enc    = (const float*)d_in[0];
  const float* ln0_g  = (const float*)d_in[1];
  const float* ln0_b  = (const float*)d_in[2];
  const float* Wq     = (const float*)d_in[3];
  const float* Wk     = (const float*)d_in[4];
  const float* Wv     = (const float*)d_in[5];
  const float* Wo     = (const float*)d_in[6];
  const float* W1     = (const float*)d_in[7];
  const float* b1     = (const float*)d_in[8];
  const float* tdelta = (const float*)d_in[9];
  const float* lr_w   = (const float*)d_in[10];
  const float* lr_b   = (const float*)d_in[11];
  const float* ttt_g  = (const float*)d_in[12];
  const float* ttt_b  = (const float*)d_in[13];
  const float* post_g = (const float*)d_in[14];
  const float* post_b = (const float*)d_in[15];
  const float* ffn_g  = (const float*)d_in[16];
  const float* ffn_b  = (const float*)d_in[17];
  const float* fw1    = (const float*)d_in[18];
  const float* fb1    = (const float*)d_in[19];
  const float* fw2    = (const float*)d_in[20];
  const float* fb2    = (const float*)d_in[21];

  char* ws = (char*)d_ws;
  short* QKV   = (short*)(ws + 0);            // 100,663,296 B (scan layout)
  short* XB    = (short*)(ws + 100663296);    //  33,554,432 B
  float* SCAN  = (float*)(ws + 100663296);    //  67,108,864 B (over XB)
  short* WQKVT = (short*)(ws + 167772160);    //   6,291,456 B
  short* WOT   = (short*)(ws + 174063616);    //   2,097,152 B
  short* FW1T  = (short*)(ws + 176160768);    //   4,194,304 B
  short* FW2T  = (short*)(ws + 180355072);    //   4,194,304 B
  short* LRWB  = (short*)(ws + 184549376);    //      65,536 B
  float* CT    = (float*)(ws + 184614912);    //     131,072 B
  float* ST    = (float*)(ws + 184745984);    //     131,072 B
  float* ETA   = (float*)(ws + 184877056);    //   2,097,152 B
  short* YB    = (short*)(ws + 0);            // reuse (post-scan)
  short* HB    = (short*)(ws + 0);            // reuse (post-Wo)
  short* T1    = (short*)(ws + 35651584);     // reuse (post-scan)
  float* R2    = (float*)d_out;

  dim3 b256(256);
  transpose_cast<<<dim3(32,32), b256, 0, stream>>>(Wq,  WQKVT,           D_, D_);
  transpose_cast<<<dim3(32,32), b256, 0, stream>>>(Wk,  WQKVT + 1048576, D_, D_);
  transpose_cast<<<dim3(32,32), b256, 0, stream>>>(Wv,  WQKVT + 2097152, D_, D_);
  transpose_cast<<<dim3(32,32), b256, 0, stream>>>(Wo,  WOT,             D_, D_);
  transpose_cast<<<dim3(64,32), b256, 0, stream>>>(fw1, FW1T,            D_, DI_);
  transpose_cast<<<dim3(32,64), b256, 0, stream>>>(fw2, FW2T,            DI_, D_);
  misc_prep<<<dim3(256), b256, 0, stream>>>(lr_w, LRWB, CT, ST);

  ln_rows<<<BL_, b256, 0, stream>>>(enc, ln0_g, ln0_b, XB);
  // QKV projection, fused RoPE, scan-layout output
  gemm_bt<0,0,0,0,1><<<dim3(24,128), b256, 0, stream>>>(XB, WQKVT, nullptr, nullptr,
                                                        nullptr, QKV, CT, ST, BL_, 3072, D_);
  eta_kernel<<<dim3(512), b256, 0, stream>>>(XB, LRWB, lr_b, ETA);
  scan_kernel<<<dim3(NH_, B_), dim3(512), 0, stream>>>(QKV, ETA, W1, b1, tdelta,
                                                       ttt_g, ttt_b, SCAN);
  ln_rows<<<BL_, b256, 0, stream>>>(SCAN, post_g, post_b, YB);
  gemm_bt<0,0,0,1,0><<<dim3(8,128), b256, 0, stream>>>(YB, WOT, nullptr, enc,
                                                       R2, nullptr, nullptr, nullptr, BL_, D_, D_);
  ln_rows<<<BL_, b256, 0, stream>>>(R2, ffn_g, ffn_b, HB);
  gemm_bt<1,1,1,0,0><<<dim3(16,128), b256, 0, stream>>>(HB, FW1T, fb1, nullptr,
                                                        nullptr, T1, nullptr, nullptr, BL_, DI_, D_);
  gemm_bt<0,0,1,1,0><<<dim3(8,128), b256, 0, stream>>>(T1, FW2T, fb2, R2,
                                                       R2, nullptr, nullptr, nullptr, BL_, D_, DI_);
}

// Round 3
// 1003.431 us; speedup vs baseline: 1.2395x; 1.0512x over previous
//
#include <hip/hip_runtime.h>
#include <hip/hip_bf16.h>
#include <stdint.h>

#define B_   8
#define L_   2048
#define D_   1024
#define NH_  32
#define M_   16
#define NM_  128
#define HD_  32
#define DI_  2048
#define BL_  16384
#define EPS_ 1e-6f

typedef __attribute__((ext_vector_type(8))) short  s16x8;
typedef __attribute__((ext_vector_type(4))) short  s16x4;
typedef __attribute__((ext_vector_type(8))) __bf16 bf16x8;
typedef __attribute__((ext_vector_type(4))) float  f32x4;

__device__ __forceinline__ float bf2f(short s){
  unsigned u = ((unsigned)(unsigned short)s) << 16;
  return __builtin_bit_cast(float, u);
}
__device__ __forceinline__ short f2bf(float f){
  unsigned u = __builtin_bit_cast(unsigned, f);
  u = u + 0x7FFFu + ((u >> 16) & 1u);   // RNE
  return (short)(u >> 16);
}
__device__ __forceinline__ float rsum16(float v){
  v += __shfl_xor(v, 1); v += __shfl_xor(v, 2);
  v += __shfl_xor(v, 4); v += __shfl_xor(v, 8);
  return v;
}
// async global->LDS, 16B per lane (dest = wave-uniform base + lane*16)
__device__ __forceinline__ void gl16(const void* g, void* l){
  __builtin_amdgcn_global_load_lds(
      (const __attribute__((address_space(1))) void*)g,
      (__attribute__((address_space(3))) void*)l, 16, 0, 0);
}

// ---------------- transpose + fp32->bf16 cast: out(Cc,R) = in(R,Cc)^T ------
__global__ __launch_bounds__(256) void transpose_cast(
    const float* __restrict__ in, short* __restrict__ out, int R, int Cc)
{
  __shared__ float t[32][33];
  const int lx = threadIdx.x & 31, ly = threadIdx.x >> 5;
  const int r0 = blockIdx.y * 32, c0 = blockIdx.x * 32;
  #pragma unroll
  for (int s = 0; s < 4; ++s){
    const int r = ly + s*8;
    t[r][lx] = in[(size_t)(r0 + r)*Cc + c0 + lx];
  }
  __syncthreads();
  #pragma unroll
  for (int s = 0; s < 4; ++s){
    const int r = ly + s*8;
    out[(size_t)(c0 + r)*R + r0 + lx] = f2bf(t[lx][r]);
  }
}

// ---------------- misc prep: lr_w cast + rope tables -----------------------
__global__ __launch_bounds__(256) void misc_prep(
    const float* __restrict__ lr_w, short* __restrict__ lrwb,
    float* __restrict__ ct, float* __restrict__ st)
{
  const int idx = blockIdx.x*256 + threadIdx.x;
  if (idx < NH_*D_){
    lrwb[idx] = f2bf(lr_w[idx]);
  } else {
    const int k = idx - NH_*D_;       // 0 .. L_*16-1
    const int l = k >> 4, j = k & 15;
    const float inv = powf(10000.f, -(float)j * (1.f/16.f));
    const float fr  = (float)l * inv;
    ct[k] = cosf(fr);
    st[k] = sinf(fr);
  }
}

// ---------------- row layernorm fp32 -> bf16 (D=1024) ----------------------
__global__ __launch_bounds__(256) void ln_rows(
    const float* __restrict__ in, const float* __restrict__ g,
    const float* __restrict__ bta, short* __restrict__ out)
{
  const int row = blockIdx.x, tid = threadIdx.x;
  const float4 v = ((const float4*)(in + (size_t)row*D_))[tid];
  float s  = v.x + v.y + v.z + v.w;
  float s2 = v.x*v.x + v.y*v.y + v.z*v.z + v.w*v.w;
  #pragma unroll
  for (int m = 1; m < 64; m <<= 1){ s += __shfl_xor(s, m); s2 += __shfl_xor(s2, m); }
  __shared__ float rs[4], rq[4];
  if ((tid & 63) == 0){ rs[tid>>6] = s; rq[tid>>6] = s2; }
  __syncthreads();
  s  = rs[0] + rs[1] + rs[2] + rs[3];
  s2 = rq[0] + rq[1] + rq[2] + rq[3];
  const float mu   = s  * (1.f/D_);
  const float var  = s2 * (1.f/D_) - mu*mu;
  const float rstd = rsqrtf(var + EPS_);
  const float4 gg = ((const float4*)g)[tid];
  const float4 bb = ((const float4*)bta)[tid];
  s16x4 o;
  o[0] = f2bf((v.x - mu)*rstd*gg.x + bb.x);
  o[1] = f2bf((v.y - mu)*rstd*gg.y + bb.y);
  o[2] = f2bf((v.z - mu)*rstd*gg.z + bb.z);
  o[3] = f2bf((v.w - mu)*rstd*gg.w + bb.w);
  ((s16x4*)(out + (size_t)row*D_))[tid] = o;
}

// ---------------- row layernorm bf16 -> bf16 (D=1024) ----------------------
__global__ __launch_bounds__(256) void ln_rows_bf(
    const short* __restrict__ in, const float* __restrict__ g,
    const float* __restrict__ bta, short* __restrict__ out)
{
  const int row = blockIdx.x, tid = threadIdx.x;
  const s16x4 v4 = ((const s16x4*)(in + (size_t)row*D_))[tid];
  float v[4];
  #pragma unroll
  for (int e = 0; e < 4; ++e) v[e] = bf2f(v4[e]);
  float s  = v[0]+v[1]+v[2]+v[3];
  float s2 = v[0]*v[0]+v[1]*v[1]+v[2]*v[2]+v[3]*v[3];
  #pragma unroll
  for (int m = 1; m < 64; m <<= 1){ s += __shfl_xor(s, m); s2 += __shfl_xor(s2, m); }
  __shared__ float rs[4], rq[4];
  if ((tid & 63) == 0){ rs[tid>>6] = s; rq[tid>>6] = s2; }
  __syncthreads();
  s  = rs[0] + rs[1] + rs[2] + rs[3];
  s2 = rq[0] + rq[1] + rq[2] + rq[3];
  const float mu   = s  * (1.f/D_);
  const float var  = s2 * (1.f/D_) - mu*mu;
  const float rstd = rsqrtf(var + EPS_);
  const float4 gg = ((const float4*)g)[tid];
  const float4 bb = ((const float4*)bta)[tid];
  s16x4 o;
  #pragma unroll
  for (int e = 0; e < 4; ++e){
    const float gv = (e==0)?gg.x:(e==1)?gg.y:(e==2)?gg.z:gg.w;
    const float bv = (e==0)?bb.x:(e==1)?bb.y:(e==2)?bb.z:bb.w;
    o[e] = f2bf((v[e] - mu)*rstd*gv + bv);
  }
  ((s16x4*)(out + (size_t)row*D_))[tid] = o;
}

// ---------------- bf16 MFMA GEMM: C(Mr,N) = A(Mr,K) @ Bt(N,K)^T ------------
// 128x128 tile, BK=32, 4 waves of 64x64. global_load_lds staging.
// QKVOUT: fused RoPE + scan-tile output {q,k,kT,vT} per (b,h,n)
template<int ACT, int OUTBF, int BIAS, int RES, int QKVOUT>
__global__ __launch_bounds__(256) void gemm_bt(
    const short* __restrict__ A, const short* __restrict__ Bt,
    const float* __restrict__ bias, const float* __restrict__ res,
    float* __restrict__ Cf, short* __restrict__ Cb,
    const float* __restrict__ ct, const float* __restrict__ st,
    int Mr, int N, int K)
{
  __shared__ __align__(16) short As[128*32];
  __shared__ __align__(16) short Bs[128*32];
  const int tid  = threadIdx.x;
  const int lane = tid & 63, wid = tid >> 6;
  const int row0 = blockIdx.y * 128, col0 = blockIdx.x * 128;
  const int wm = (wid >> 1) * 64, wn = (wid & 1) * 64;
  f32x4 acc[4][4] = {};

  const int sr = tid >> 2, sk = (tid & 3) * 8;
  const short* gA0 = A  + (size_t)(row0 + sr)      * K + sk;
  const short* gA1 = A  + (size_t)(row0 + sr + 64) * K + sk;
  const short* gB0 = Bt + (size_t)(col0 + sr)      * K + sk;
  const short* gB1 = Bt + (size_t)(col0 + sr + 64) * K + sk;
  short* lA0 = As + 8*tid;  short* lA1 = As + 2048 + 8*tid;
  short* lB0 = Bs + 8*tid;  short* lB1 = Bs + 2048 + 8*tid;

  const int fr = lane & 15, fk = (lane >> 4) * 8;
  const int nK = K >> 5;
  for (int kt = 0; kt < nK; ++kt){
    __syncthreads();
    const int ko = kt << 5;
    gl16(gA0 + ko, lA0);
    gl16(gA1 + ko, lA1);
    gl16(gB0 + ko, lB0);
    gl16(gB1 + ko, lB1);
    asm volatile("s_waitcnt vmcnt(0)" ::: "memory");
    __syncthreads();
    bf16x8 af[4], bfv[4];
    #pragma unroll
    for (int f = 0; f < 4; ++f){
      af[f]  = __builtin_bit_cast(bf16x8, *(const s16x8*)(As + (wm + f*16 + fr)*32 + fk));
      bfv[f] = __builtin_bit_cast(bf16x8, *(const s16x8*)(Bs + (wn + f*16 + fr)*32 + fk));
    }
    #pragma unroll
    for (int i = 0; i < 4; ++i)
      #pragma unroll
      for (int j = 0; j < 4; ++j)
        acc[i][j] = __builtin_amdgcn_mfma_f32_16x16x32_bf16(af[i], bfv[j], acc[i][j], 0, 0, 0);
  }
  const int cr = (lane >> 4) * 4, cc = lane & 15;
  if (QKVOUT){
    const int part = col0 >> 10;   // 0=q, 1=k, 2=v (uniform per block)
    #pragma unroll
    for (int i = 0; i < 4; ++i){
      #pragma unroll
      for (int r = 0; r < 4; ++r){
        const int gr = row0 + wm + i*16 + cr + r;
        const int bidx = gr >> 11, l = gr & (L_-1);
        const int nn = l >> 4, ii = l & 15;
        if (part < 2){
          const float cv = ct[l*16 + cc], sv = st[l*16 + cc];
          #pragma unroll
          for (int jp = 0; jp < 2; ++jp){
            const int j0 = jp*2;
            const int gc = col0 + wn + j0*16 + cc;
            const int hh = (gc & 1023) >> 5;     // dd = cc, pair = cc+16
            short* tile = Cb + ((size_t)(bidx*NH_ + hh)*NM_ + nn)*2048;
            const float x0 = acc[i][j0][r], x1 = acc[i][j0+1][r];
            const short r0 = f2bf(x0*cv - x1*sv);
            const short r1 = f2bf(x1*cv + x0*sv);
            if (part == 0){
              tile[ii*32 + cc]      = r0;
              tile[ii*32 + cc + 16] = r1;
            } else {
              tile[512 + ii*32 + cc]      = r0;
              tile[512 + ii*32 + cc + 16] = r1;
              tile[1024 + cc*16 + ii]        = r0;   // kT
              tile[1024 + (cc+16)*16 + ii]   = r1;
            }
          }
        } else {
          #pragma unroll
          for (int j = 0; j < 4; ++j){
            const int gc = col0 + wn + j*16 + cc;
            const int hh = (gc & 1023) >> 5, dd = gc & 31;
            short* tile = Cb + ((size_t)(bidx*NH_ + hh)*NM_ + nn)*2048;
            tile[1536 + dd*16 + ii] = f2bf(acc[i][j][r]);   // vT
          }
        }
      }
    }
    return;
  }
  #pragma unroll
  for (int i = 0; i < 4; ++i){
    #pragma unroll
    for (int j = 0; j < 4; ++j){
      const int gc = col0 + wn + j*16 + cc;
      float bv = 0.f;
      if (BIAS) bv = bias[gc];
      #pragma unroll
      for (int r = 0; r < 4; ++r){
        const int gr = row0 + wm + i*16 + cr + r;
        float v = acc[i][j][r] + bv;
        if (RES) v += res[(size_t)gr*N + gc];
        if (ACT == 1) v = fmaxf(v, 0.f);
        if (OUTBF) Cb[(size_t)gr*N + gc] = f2bf(v);
        else       Cf[(size_t)gr*N + gc] = v;
      }
    }
  }
}

// ---------------- eta: sigmoid(x . lr_w[h] + lr_b[h]) / HD -----------------
__global__ __launch_bounds__(256) void eta_kernel(
    const short* __restrict__ xb, const short* __restrict__ lrwb,
    const float* __restrict__ lr_b, float* __restrict__ eta)
{
  __shared__ __align__(16) short wl[NH_*D_];   // 64 KB
  __shared__ __align__(16) short xr[D_];
  const int tid = threadIdx.x;
  const int wid = tid >> 6, lane = tid & 63;
  #pragma unroll
  for (int s = 0; s < 16; ++s){
    const int e8 = tid + 256*s;
    ((s16x8*)wl)[e8] = ((const s16x8*)lrwb)[e8];
  }
  for (int tk = 0; tk < 32; ++tk){
    const int token = blockIdx.x*32 + tk;
    __syncthreads();
    if (tid < 128) ((s16x8*)xr)[tid] = ((const s16x8*)(xb + (size_t)token*D_))[tid];
    __syncthreads();
    const s16x8 x0 = ((const s16x8*)xr)[lane*2];
    const s16x8 x1 = ((const s16x8*)xr)[lane*2 + 1];
    #pragma unroll 1
    for (int hh = 0; hh < 8; ++hh){
      const int h = wid*8 + hh;
      const s16x8 w0 = ((const s16x8*)(wl + h*D_))[lane*2];
      const s16x8 w1 = ((const s16x8*)(wl + h*D_))[lane*2 + 1];
      float s = 0.f;
      #pragma unroll
      for (int e = 0; e < 8; ++e)
        s += bf2f(x0[e])*bf2f(w0[e]) + bf2f(x1[e])*bf2f(w1[e]);
      #pragma unroll
      for (int m = 1; m < 64; m <<= 1) s += __shfl_xor(s, m);
      if (lane == 0){
        const float v = 1.f/(1.f + __expf(-(s + lr_b[h]))) * (1.f/32.f);
        const int bidx = token >> 11, l = token & (L_-1), n = l >> 4, im = l & 15;
        eta[(((size_t)bidx*NH_ + h)*NM_ + n)*M_ + im] = v;
      }
    }
  }
}

// ---------------- TTT scan v3: one wave per (b,h), full MFMA ----------------
// tile layout per (b,h,n), 2048 shorts: q[16][32] | k[16][32] | kT[32][16] | vT[32][16]
struct Pf {
  s16x8 qA, kA, kTq0, kTq1;
  s16x4 kTe0, kTe1, vTe0, vTe1;
  f32x4 lr0, lr1, lr2, lr3;
};

__global__ __launch_bounds__(64) void scan_kernel(
    const short* __restrict__ Q5, const float* __restrict__ eta,
    const float* __restrict__ W1, const float* __restrict__ b1,
    const float* __restrict__ tdelta, const float* __restrict__ lng,
    const float* __restrict__ lnb, short* __restrict__ out)
{
  const int bh = blockIdx.x;
  const int h = bh & 31, b = bh >> 5;
  const int lane = threadIdx.x;
  const int li = lane & 15, lh = lane >> 4;

  __shared__ __align__(16) short WT[32*40];   // W^T bf16, pitch 40 shorts
  __shared__ __align__(16) short GT[32*24];   // grad^T bf16, pitch 24
  __shared__ __align__(16) float AT[16*20];   // attn f32, pitch 20
  __shared__ __align__(16) short QL[16*40];   // q row-major, pitch 40

  // W in four 16x16 C-layout quadrants: Wq[rb][cb][r] = W[16rb+4lh+r][16cb+li]
  f32x4 Wq[2][2];
  #pragma unroll
  for (int rb = 0; rb < 2; ++rb)
    #pragma unroll
    for (int cb = 0; cb < 2; ++cb)
      #pragma unroll
      for (int r = 0; r < 4; ++r)
        Wq[rb][cb][r] = W1[h*1024 + (16*rb + 4*lh + r)*32 + 16*cb + li];

  float bb[2], lw[2], lbv[2];
  #pragma unroll
  for (int hh = 0; hh < 2; ++hh){
    bb[hh]  = b1[h*32 + 16*hh + li];
    lw[hh]  = lng[h*32 + 16*hh + li];
    lbv[hh] = lnb[h*32 + 16*hh + li];
  }
  const float tok_i = fmaxf(1.f/(float)(li+1) + tdelta[li], 0.f);
  const float lef   = fmaxf(1.f/16.f + tdelta[15], 0.f);

  const short* chain = Q5 + (size_t)bh * (NM_*2048);
  const float* ech   = eta + (size_t)bh * (NM_*16);
  short* outp = out + (size_t)b*L_*D_ + h*32;

  // write W^T bf16 to LDS (for B-fragment reads)
  auto writeWT = [&]{
    #pragma unroll
    for (int rb = 0; rb < 2; ++rb)
      #pragma unroll
      for (int cb = 0; cb < 2; ++cb){
        s16x4 p;
        #pragma unroll
        for (int r = 0; r < 4; ++r) p[r] = f2bf(Wq[rb][cb][r]);
        *(s16x4*)(WT + (16*cb + li)*40 + 16*rb + 4*lh) = p;
      }
  };
  writeWT();

  auto load_tile = [&](int n) -> Pf {
    const short* t = chain + (size_t)n*2048;
    const float* e = ech + n*16;
    Pf p;
    p.qA   = *(const s16x8*)(t + li*32 + 8*lh);
    p.kA   = *(const s16x8*)(t + 512 + li*32 + 8*lh);
    p.kTq0 = *(const s16x8*)(t + 1024 + li*16 + 8*(lh & 1));
    p.kTq1 = *(const s16x8*)(t + 1024 + (16 + li)*16 + 8*(lh & 1));
    p.kTe0 = *(const s16x4*)(t + 1024 + li*16 + 4*lh);
    p.kTe1 = *(const s16x4*)(t + 1024 + (16 + li)*16 + 4*lh);
    p.vTe0 = *(const s16x4*)(t + 1536 + li*16 + 4*lh);
    p.vTe1 = *(const s16x4*)(t + 1536 + (16 + li)*16 + 4*lh);
    p.lr0 = *(const f32x4*)(e);
    p.lr1 = *(const f32x4*)(e + 4);
    p.lr2 = *(const f32x4*)(e + 8);
    p.lr3 = *(const f32x4*)(e + 12);
    return p;
  };

  Pf cur = load_tile(0);
  #pragma unroll 1
  for (int n = 0; n < NM_; ++n){
    Pf nxt = load_tile(n + 1 < NM_ ? n + 1 : NM_ - 1);

    const bf16x8 qAf = __builtin_bit_cast(bf16x8, cur.qA);
    const bf16x8 kAf = __builtin_bit_cast(bf16x8, cur.kA);
    bf16x8 Wf[2];
    Wf[0] = __builtin_bit_cast(bf16x8, *(const s16x8*)(WT + li*40 + 8*lh));
    Wf[1] = __builtin_bit_cast(bf16x8, *(const s16x8*)(WT + (16 + li)*40 + 8*lh));

    // q row-major into LDS for transpose reads at output time
    *(s16x8*)(QL + li*40 + 8*lh) = cur.qA;

    // Z1 = k@W + b ; Y = q@W + b ; a = q@kT
    f32x4 zac[2], yac[2], aac = {};
    #pragma unroll
    for (int hh = 0; hh < 2; ++hh){
      f32x4 c0; c0[0]=bb[hh]; c0[1]=bb[hh]; c0[2]=bb[hh]; c0[3]=bb[hh];
      zac[hh] = __builtin_amdgcn_mfma_f32_16x16x32_bf16(kAf, Wf[hh], c0, 0,0,0);
      yac[hh] = __builtin_amdgcn_mfma_f32_16x16x32_bf16(qAf, Wf[hh], c0, 0,0,0);
    }
    aac = __builtin_amdgcn_mfma_f32_16x16x32_bf16(qAf, kAf, aac, 0,0,0);

    #pragma unroll
    for (int r = 0; r < 4; ++r)
      AT[(4*lh + r)*20 + li] = aac[r];

    // grad = ln_l2_bwd(Z1, v-k), elementwise in C-layout
    float xh[2][4], grad[2][4], rstdv[4];
    #pragma unroll
    for (int r = 0; r < 4; ++r){
      float s  = zac[0][r] + zac[1][r];
      float q2 = zac[0][r]*zac[0][r] + zac[1][r]*zac[1][r];
      s = rsum16(s); q2 = rsum16(q2);
      const float mu  = s * (1.f/32.f);
      const float var = q2 * (1.f/32.f) - mu*mu;
      const float rstd = rsqrtf(var + EPS_);
      rstdv[r] = rstd;
      xh[0][r] = (zac[0][r] - mu) * rstd;
      xh[1][r] = (zac[1][r] - mu) * rstd;
    }
    #pragma unroll
    for (int r = 0; r < 4; ++r){
      const float t0 = bf2f(cur.vTe0[r]) - bf2f(cur.kTe0[r]);
      const float t1 = bf2f(cur.vTe1[r]) - bf2f(cur.kTe1[r]);
      const float g0 = (xh[0][r]*lw[0] + lbv[0] - t0)*lw[0];
      const float g1 = (xh[1][r]*lw[1] + lbv[1] - t1)*lw[1];
      float sg  = rsum16(g0 + g1);
      float sgx = rsum16(g0*xh[0][r] + g1*xh[1][r]);
      const float f = rstdv[r] * (1.f/32.f);
      grad[0][r] = (32.f*g0 - sg - xh[0][r]*sgx) * f;
      grad[1][r] = (32.f*g1 - sg - xh[1][r]*sgx) * f;
    }

    // grad^T bf16 to LDS
    #pragma unroll
    for (int hh = 0; hh < 2; ++hh){
      s16x4 p;
      #pragma unroll
      for (int r = 0; r < 4; ++r) p[r] = f2bf(grad[hh][r]);
      *(s16x4*)(GT + (16*hh + li)*24 + 4*lh) = p;
    }

    // grad B-fragments (rows 16..31 of zero-extended K are 0)
    const s16x8 zz = {};
    bf16x8 gf[2];
    gf[0] = __builtin_bit_cast(bf16x8, (lh < 2) ? *(const s16x8*)(GT + li*24 + 8*lh) : zz);
    gf[1] = __builtin_bit_cast(bf16x8, (lh < 2) ? *(const s16x8*)(GT + (16 + li)*24 + 8*lh) : zz);

    // P fragment: P[i][j] = -tok_i*lr_j*(1+a[i][j])*[j<=i]  (negated for subtraction)
    f32x4 arA = {}, arB = {};
    if (lh < 2){
      arA = *(const f32x4*)(AT + li*20 + 8*lh);
      arB = *(const f32x4*)(AT + li*20 + 8*lh + 4);
    }
    const f32x4 plA = (lh & 1) ? cur.lr2 : cur.lr0;
    const f32x4 plB = (lh & 1) ? cur.lr3 : cur.lr1;
    s16x8 pp;
    #pragma unroll
    for (int jj = 0; jj < 8; ++jj){
      const float av  = (jj < 4) ? arA[jj] : arB[jj - 4];
      const float lrv = (jj < 4) ? plA[jj] : plB[jj - 4];
      const bool ok = (lh < 2) && (8*lh + jj <= li);
      pp[jj] = f2bf(ok ? -tok_i * lrv * (1.f + av) : 0.f);
    }
    const bf16x8 pAf = __builtin_bit_cast(bf16x8, pp);

    // Z1_bar = Y - P@grad
    #pragma unroll
    for (int hh = 0; hh < 2; ++hh)
      yac[hh] = __builtin_amdgcn_mfma_f32_16x16x32_bf16(pAf, gf[hh], yac[hh], 0,0,0);

    // W update: W -= (lef*lr (.) k)^T @ grad  (4 quadrant MFMAs, A pre-negated)
    #pragma unroll
    for (int rb = 0; rb < 2; ++rb){
      const s16x8 kq = rb ? cur.kTq1 : cur.kTq0;
      s16x8 au;
      #pragma unroll
      for (int jj = 0; jj < 8; ++jj){
        const float lrv = (jj < 4) ? plA[jj] : plB[jj - 4];
        au[jj] = f2bf((lh < 2) ? -lef * lrv * bf2f(kq[jj]) : 0.f);
      }
      const bf16x8 af = __builtin_bit_cast(bf16x8, au);
      #pragma unroll
      for (int cb = 0; cb < 2; ++cb)
        Wq[rb][cb] = __builtin_amdgcn_mfma_f32_16x16x32_bf16(af, gf[cb], Wq[rb][cb], 0,0,0);
    }

    // b update: b[c] -= lef * sum_j lr_j * grad[j][c]
    f32x4 lrq;
    { const f32x4 t0 = (lh & 1) ? cur.lr1 : cur.lr0;
      const f32x4 t1 = (lh & 1) ? cur.lr3 : cur.lr2;
      lrq = (lh & 2) ? t1 : t0; }
    #pragma unroll
    for (int hh = 0; hh < 2; ++hh){
      float t = 0.f;
      #pragma unroll
      for (int r = 0; r < 4; ++r) t += lrq[r]*grad[hh][r];
      t += __shfl_xor(t, 16); t += __shfl_xor(t, 32);
      bb[hh] -= lef * t;
    }

    // out = q + ln_fwd(Z1_bar)
    #pragma unroll
    for (int r = 0; r < 4; ++r){
      float s  = yac[0][r] + yac[1][r];
      float q2 = yac[0][r]*yac[0][r] + yac[1][r]*yac[1][r];
      s = rsum16(s); q2 = rsum16(q2);
      const float mu   = s * (1.f/32.f);
      const float var  = q2 * (1.f/32.f) - mu*mu;
      const float rstd = rsqrtf(var + EPS_);
      const int row = 4*lh + r;
      #pragma unroll
      for (int hh = 0; hh < 2; ++hh){
        const float qv = bf2f(QL[row*40 + 16*hh + li]);
        const float o  = qv + (yac[hh][r] - mu)*rstd*lw[hh] + lbv[hh];
        outp[(size_t)(n*16 + row)*D_ + 16*hh + li] = f2bf(o);
      }
    }

    // W^T for next step (W just updated)
    writeWT();
    cur = nxt;
  }
}

// ---------------------------------------------------------------------------
extern "C" void kernel_launch(void* const* d_in, const int* in_sizes, int n_in,
                              void* d_out, int out_size, void* d_ws, size_t ws_size,
                              hipStream_t stream)
{
  const float* enc    = (const float*)d_in[0];
  const float* ln0_g  = (const float*)d_in[1];
  const float* ln0_b  = (const float*)d_in[2];
  const float* Wq     = (const float*)d_in[3];
  const float* Wk     = (const float*)d_in[4];
  const float* Wv     = (const float*)d_in[5];
  const float* Wo     = (const float*)d_in[6];
  const float* W1     = (const float*)d_in[7];
  const float* b1     = (const float*)d_in[8];
  const float* tdelta = (const float*)d_in[9];
  const float* lr_w   = (const float*)d_in[10];
  const float* lr_b   = (const float*)d_in[11];
  const float* ttt_g  = (const float*)d_in[12];
  const float* ttt_b  = (const float*)d_in[13];
  const float* post_g = (const float*)d_in[14];
  const float* post_b = (const float*)d_in[15];
  const float* ffn_g  = (const float*)d_in[16];
  const float* ffn_b  = (const float*)d_in[17];
  const float* fw1    = (const float*)d_in[18];
  const float* fb1    = (const float*)d_in[19];
  const float* fw2    = (const float*)d_in[20];
  const float* fb2    = (const float*)d_in[21];

  char* ws = (char*)d_ws;
  short* Q5    = (short*)(ws + 0);            // 134,217,728 B (scan tiles)
  short* XB    = (short*)(ws + 134217728);    //  33,554,432 B
  short* SCANB = (short*)(ws + 134217728);    //  alias XB (XB dead pre-scan)
  short* WQKVT = (short*)(ws + 167772160);    //   6,291,456 B
  short* WOT   = (short*)(ws + 174063616);    //   2,097,152 B
  short* FW1T  = (short*)(ws + 176160768);    //   4,194,304 B
  short* FW2T  = (short*)(ws + 180355072);    //   4,194,304 B
  short* LRWB  = (short*)(ws + 184549376);    //      65,536 B
  float* CT    = (float*)(ws + 184614912);    //     131,072 B
  float* ST    = (float*)(ws + 184745984);    //     131,072 B
  float* ETA   = (float*)(ws + 184877056);    //   2,097,152 B
  short* YB    = (short*)(ws + 0);            // alias Q5 (post-scan)
  short* HB    = (short*)(ws + 33554432);     // alias Q5
  short* T1    = (short*)(ws + 67108864);     // alias Q5
  float* R2    = (float*)d_out;

  dim3 b256(256);
  transpose_cast<<<dim3(32,32), b256, 0, stream>>>(Wq,  WQKVT,           D_, D_);
  transpose_cast<<<dim3(32,32), b256, 0, stream>>>(Wk,  WQKVT + 1048576, D_, D_);
  transpose_cast<<<dim3(32,32), b256, 0, stream>>>(Wv,  WQKVT + 2097152, D_, D_);
  transpose_cast<<<dim3(32,32), b256, 0, stream>>>(Wo,  WOT,             D_, D_);
  transpose_cast<<<dim3(64,32), b256, 0, stream>>>(fw1, FW1T,            D_, DI_);
  transpose_cast<<<dim3(32,64), b256, 0, stream>>>(fw2, FW2T,            DI_, D_);
  misc_prep<<<dim3(256), b256, 0, stream>>>(lr_w, LRWB, CT, ST);

  ln_rows<<<BL_, b256, 0, stream>>>(enc, ln0_g, ln0_b, XB);
  gemm_bt<0,0,0,0,1><<<dim3(24,128), b256, 0, stream>>>(XB, WQKVT, nullptr, nullptr,
                                                        nullptr, Q5, CT, ST, BL_, 3072, D_);
  eta_kernel<<<dim3(512), b256, 0, stream>>>(XB, LRWB, lr_b, ETA);
  scan_kernel<<<dim3(256), dim3(64), 0, stream>>>(Q5, ETA, W1, b1, tdelta,
                                                  ttt_g, ttt_b, SCANB);
  ln_rows_bf<<<BL_, b256, 0, stream>>>(SCANB, post_g, post_b, YB);
  gemm_bt<0,0,0,1,0><<<dim3(8,128), b256, 0, stream>>>(YB, WOT, nullptr, enc,
                                                       R2, nullptr, nullptr, nullptr, BL_, D_, D_);
  ln_rows<<<BL_, b256, 0, stream>>>(R2, ffn_g, ffn_b, HB);
  gemm_bt<1,1,1,0,0><<<dim3(16,128), b256, 0, stream>>>(HB, FW1T, fb1, nullptr,
                                                        nullptr, T1, nullptr, nullptr, BL_, DI_, D_);
  gemm_bt<0,0,1,1,0><<<dim3(8,128), b256, 0, stream>>>(T1, FW2T, fb2, R2,
                                                       R2, nullptr, nullptr, nullptr, BL_, D_, DI_);
}